// Round 11
// baseline (133.360 us; speedup 1.0000x reference)
//
#include <hip/hip_runtime.h>
#include <math.h>

// ---------------- problem constants ----------------
#define NBLOCKS 2048
#define THREADS 256               // 4 waves/block
#define TILE 64
#define POS_PER_BLOCK 512         // one j-row per block
#define NPAIR 4                   // loop iters; each handles tiles it and it+4

typedef __attribute__((ext_vector_type(8)))  short  short8;   // MFMA A/B frag
typedef __attribute__((ext_vector_type(16))) float  float16;  // 32x32 C/D frag

__device__ __forceinline__ unsigned cvt_pk(float lo, float hi) {
    unsigned r;
    asm("v_cvt_pk_bf16_f32 %0, %1, %2" : "=v"(r) : "v"(lo), "v"(hi));
    return r;
}

// Fully in-register 3-layer MLP per wave (r10-verified mappings), now with
// TWO independent position-tiles interleaved per loop body: 4 L2 acc-chains,
// 8 L1 chains, 2 L3 chains -> MFMA latency shadows filled by the other tile.
__global__ __launch_bounds__(256, 2)
void crpb_mfma10(const float* __restrict__ gq,   // (512,3)
                 const float* __restrict__ gkv,  // (4,512,3)
                 const float* __restrict__ W1,   // (3,128)
                 const float* __restrict__ b1,   // (128,)
                 const float* __restrict__ W2,   // (128,128)
                 const float* __restrict__ b2,   // (128,)
                 const float* __restrict__ W3,   // (128,4)
                 const float* __restrict__ b3,   // (4,)
                 float* __restrict__ out)        // (16,512,512)
{
    __shared__ __align__(16) float red[8][2][4][64];   // 16 KB partials

    const int tid  = threadIdx.x;
    const int lane = tid & 63;
    const int w    = __builtin_amdgcn_readfirstlane(tid >> 6);  // 0..3
    const int l31  = lane & 31;
    const int lh   = lane >> 5;
    const bool l0  = (lh == 0);

    const int ct2 = w & 1;            // out-ch half
    const int pg  = w >> 1;           // pos-group within 64-tile
    const int pofs = pg * 32 + l31;

    float16 z16;
    #pragma unroll
    for (int r = 0; r < 16; ++r) z16[r] = 0.0f;

    // ---- layer-1 A-frags (16 VGPRs): W1 hi/lo + b1 folded (r10-verified) ----
    short8 w1f[4];
    #pragma unroll
    for (int T = 0; T < 4; ++T) {
        const int ch = 32 * T + l31;
        const float w0 = W1[ch], w1v = W1[128 + ch], w2v = W1[256 + ch], b1v = b1[ch];
        const float w0h = __uint_as_float(cvt_pk(w0, w0) << 16);
        const float w1h = __uint_as_float(cvt_pk(w1v, w1v) << 16);
        const float w2h = __uint_as_float(cvt_pk(w2v, w2v) << 16);
        const float b1h = __uint_as_float(cvt_pk(b1v, b1v) << 16);
        const float w0l = w0 - w0h, w1l = w1v - w1h, w2l = w2v - w2h, b1l = b1v - b1h;
        unsigned d[4];
        d[0] = l0 ? cvt_pk(w0h, w0l) : cvt_pk(w2h, b1h);
        d[1] = l0 ? cvt_pk(w0h, w1h) : cvt_pk(b1l, 0.0f);
        d[2] = l0 ? cvt_pk(w1l, w1h) : 0u;
        d[3] = l0 ? cvt_pk(w2h, w2l) : 0u;
        __builtin_memcpy(&w1f[T], d, 16);
    }

    // ---- W2^T stationary A-frags, k-permuted to layer-1 C-octets (64 VGPRs) ----
    short8 a2fT[2][8];
    #pragma unroll
    for (int ot = 0; ot < 2; ++ot) {
        const int m = ct2 * 64 + ot * 32 + l31;
        #pragma unroll
        for (int ks = 0; ks < 8; ++ks) {
            unsigned t0[4];
            #pragma unroll
            for (int t = 0; t < 4; ++t) {
                const int s  = 8 * lh + 2 * t;
                const int d0 = 16 * ks + (s & 3) + 8 * ((s >> 2) & 1) + 4 * (s >> 3);
                t0[t] = cvt_pk(W2[d0 * 128 + m], W2[(d0 + 1) * 128 + m]);
            }
            __builtin_memcpy(&a2fT[ot][ks], t0, 16);
        }
    }

    // ---- b2 K-step frags (8 VGPRs) + constant-1 B (4 VGPRs) ----
    short8 a2b2[2];
    #pragma unroll
    for (int ot = 0; ot < 2; ++ot) {
        const int ch = ct2 * 64 + ot * 32 + l31;
        const float b2v = b2[ch];
        const float b2h = __uint_as_float(cvt_pk(b2v, b2v) << 16);
        const float b2l = b2v - b2h;
        unsigned d[4];
        d[0] = l0 ? cvt_pk(b2h, b2l) : 0u;
        d[1] = 0; d[2] = 0; d[3] = 0;
        __builtin_memcpy(&a2b2[ot], d, 16);
    }
    short8 bconst;
    {
        unsigned d[4];
        d[0] = l0 ? 0x3F803F80u : 0u;   // bf16(1.0) x2
        d[1] = 0; d[2] = 0; d[3] = 0;
        __builtin_memcpy(&bconst, d, 16);
    }

    // ---- W3 A-frags (16 VGPRs), r9-verified in-register layer-3 mapping ----
    short8 w3a[2][2];
    #pragma unroll
    for (int ot = 0; ot < 2; ++ot) {
        #pragma unroll
        for (int m2 = 0; m2 < 2; ++m2) {
            unsigned tt[4];
            #pragma unroll
            for (int t = 0; t < 4; ++t) {
                const int chl = ((2 * t) & 3) + 8 * ((2 * t) >> 2) + 4 * lh + 16 * m2;
                const int ch0 = ct2 * 64 + ot * 32 + chl, ch1 = ch0 + 1;
                const float lo = (l31 < 4) ? W3[ch0 * 4 + l31] : 0.0f;
                const float hi = (l31 < 4) ? W3[ch1 * 4 + l31] : 0.0f;
                tt[t] = cvt_pk(lo, hi);
            }
            __builtin_memcpy(&w3a[ot][m2], tt, 16);
        }
    }

    // ---- block-constant indices: one j-row ----
    const int posblock = blockIdx.x * POS_PER_BLOCK;
    const int bb = posblock >> 18;
    const int i  = (posblock >> 9) & 511;
    const float q0 = gq[i * 3 + 0], q1 = gq[i * 3 + 1], q2 = gq[i * 3 + 2];
    const float* kvrow = gkv + (size_t)(bb << 9) * 3;

    // prefetch kv for tile 0 (stream A) and tile 4 (stream B)
    const float* kpa = kvrow + (size_t)pofs * 3;
    const float* kpb = kvrow + (size_t)(4 * TILE + pofs) * 3;
    float kvA0 = kpa[0], kvA1 = kpa[1], kvA2 = kpa[2];
    float kvB0 = kpb[0], kvB1 = kpb[1], kvB2 = kpb[2];

    // build layer-1 B-frag from features (branchless lh select)
    auto buildBF = [&](float c0, float c1, float c2) -> short8 {
        const float f0 = copysignf(__logf(1.0f + fabsf(c0)), c0);
        const float f1 = copysignf(__logf(1.0f + fabsf(c1)), c1);
        const float f2 = copysignf(__logf(1.0f + fabsf(c2)), c2);
        const unsigned u0 = cvt_pk(f0, f0), u2 = cvt_pk(f2, f2);
        const float f0h = __uint_as_float(u0 << 16);
        const float f1h = __uint_as_float(cvt_pk(f1, f1) << 16);
        const float f2h = __uint_as_float(u2 << 16);
        const float f0l = f0 - f0h, f1l = f1 - f1h, f2l = f2 - f2h;
        unsigned d[4];
        d[0] = l0 ? u0 : cvt_pk(f2l, 1.0f);
        d[1] = l0 ? cvt_pk(f0l, f1) : 0x00003F80u;   // (1.0,0) packed for lh1
        d[2] = l0 ? cvt_pk(f1, f1l) : 0u;
        d[3] = l0 ? u2 : 0u;
        short8 bf; __builtin_memcpy(&bf, d, 16);
        return bf;
    };

    #pragma unroll
    for (int it = 0; it < NPAIR; ++it) {
        // ---- features for both tiles + next-iter prefetch (wrapped) ----
        const float cA0 = q0 - kvA0, cA1 = q1 - kvA1, cA2 = q2 - kvA2;
        const float cB0 = q0 - kvB0, cB1 = q1 - kvB1, cB2 = q2 - kvB2;
        {
            const int nx = (it + 1) & 3;
            const float* na = kvrow + (size_t)(nx * TILE + pofs) * 3;
            const float* nb = kvrow + (size_t)((nx + 4) * TILE + pofs) * 3;
            kvA0 = na[0]; kvA1 = na[1]; kvA2 = na[2];
            kvB0 = nb[0]; kvB1 = nb[1]; kvB2 = nb[2];
        }
        const short8 bfA = buildBF(cA0, cA1, cA2);
        const short8 bfB = buildBF(cB0, cB1, cB2);

        // ---- acc init = b2 via constant-1.0 K-step (4 independent chains) ----
        float16 aA0 = __builtin_amdgcn_mfma_f32_32x32x16_bf16(a2b2[0], bconst, z16, 0, 0, 0);
        float16 aA1 = __builtin_amdgcn_mfma_f32_32x32x16_bf16(a2b2[1], bconst, z16, 0, 0, 0);
        float16 aB0 = __builtin_amdgcn_mfma_f32_32x32x16_bf16(a2b2[0], bconst, z16, 0, 0, 0);
        float16 aB1 = __builtin_amdgcn_mfma_f32_32x32x16_bf16(a2b2[1], bconst, z16, 0, 0, 0);

        // ---- interleaved L1 -> pack -> L2 for both tiles ----
        #pragma unroll
        for (int T = 0; T < 4; ++T) {
            float16 cA = __builtin_amdgcn_mfma_f32_32x32x16_bf16(w1f[T], bfA, z16, 0, 0, 0);
            float16 cB = __builtin_amdgcn_mfma_f32_32x32x16_bf16(w1f[T], bfB, z16, 0, 0, 0);
            #pragma unroll
            for (int h2 = 0; h2 < 2; ++h2) {        // ks = 2T + h2
                unsigned pkA[4], pkB[4];
                #pragma unroll
                for (int t = 0; t < 4; ++t) {
                    pkA[t] = cvt_pk(fmaxf(cA[8 * h2 + 2 * t], 0.f),
                                    fmaxf(cA[8 * h2 + 2 * t + 1], 0.f));
                    pkB[t] = cvt_pk(fmaxf(cB[8 * h2 + 2 * t], 0.f),
                                    fmaxf(cB[8 * h2 + 2 * t + 1], 0.f));
                }
                short8 fA, fB;
                __builtin_memcpy(&fA, pkA, 16);
                __builtin_memcpy(&fB, pkB, 16);
                const int ks = 2 * T + h2;
                aA0 = __builtin_amdgcn_mfma_f32_32x32x16_bf16(a2fT[0][ks], fA, aA0, 0, 0, 0);
                aB0 = __builtin_amdgcn_mfma_f32_32x32x16_bf16(a2fT[0][ks], fB, aB0, 0, 0, 0);
                aA1 = __builtin_amdgcn_mfma_f32_32x32x16_bf16(a2fT[1][ks], fA, aA1, 0, 0, 0);
                aB1 = __builtin_amdgcn_mfma_f32_32x32x16_bf16(a2fT[1][ks], fB, aB1, 0, 0, 0);
            }
        }

        // ---- layer-3 in-register for both tiles + partial stores ----
        #pragma unroll
        for (int s = 0; s < 2; ++s) {
            const float16& x0 = s ? aB0 : aA0;
            const float16& x1 = s ? aB1 : aA1;
            unsigned pa0[4], pa1[4], pb0[4], pb1[4];
            #pragma unroll
            for (int t = 0; t < 4; ++t) {
                pa0[t] = cvt_pk(fmaxf(x0[2 * t], 0.f),     fmaxf(x0[2 * t + 1], 0.f));
                pa1[t] = cvt_pk(fmaxf(x0[8 + 2 * t], 0.f), fmaxf(x0[8 + 2 * t + 1], 0.f));
                pb0[t] = cvt_pk(fmaxf(x1[2 * t], 0.f),     fmaxf(x1[2 * t + 1], 0.f));
                pb1[t] = cvt_pk(fmaxf(x1[8 + 2 * t], 0.f), fmaxf(x1[8 + 2 * t + 1], 0.f));
            }
            short8 fa0, fa1, fb0, fb1;
            __builtin_memcpy(&fa0, pa0, 16); __builtin_memcpy(&fa1, pa1, 16);
            __builtin_memcpy(&fb0, pb0, 16); __builtin_memcpy(&fb1, pb1, 16);
            float16 p;
            p = __builtin_amdgcn_mfma_f32_32x32x16_bf16(w3a[0][0], fa0, z16, 0, 0, 0);
            p = __builtin_amdgcn_mfma_f32_32x32x16_bf16(w3a[0][1], fa1, p, 0, 0, 0);
            p = __builtin_amdgcn_mfma_f32_32x32x16_bf16(w3a[1][0], fb0, p, 0, 0, 0);
            p = __builtin_amdgcn_mfma_f32_32x32x16_bf16(w3a[1][1], fb1, p, 0, 0, 0);
            const int tix = it + 4 * s;
            if (l0) {
                #pragma unroll
                for (int o = 0; o < 4; ++o)
                    red[tix][ct2][o][pofs] = p[o];
            }
        }
    }

    __syncthreads();   // single barrier

    // ---- reduce + coalesced store ----
    {
        const int o = tid >> 6, pos = tid & 63;
        const float b3v = b3[o];
        float* obase = out + ((size_t)((bb << 2) + o) << 18) + ((size_t)i << 9) + pos;
        #pragma unroll
        for (int t8 = 0; t8 < 8; ++t8) {
            const float v = b3v + red[t8][0][o][pos] + red[t8][1][o][pos];
            obase[t8 * TILE] = v;
        }
    }
}

extern "C" void kernel_launch(void* const* d_in, const int* in_sizes, int n_in,
                              void* d_out, int out_size, void* d_ws, size_t ws_size,
                              hipStream_t stream) {
    const float* gq  = (const float*)d_in[0];
    const float* gkv = (const float*)d_in[1];
    const float* W1  = (const float*)d_in[2];
    const float* b1  = (const float*)d_in[3];
    const float* W2  = (const float*)d_in[4];
    const float* b2  = (const float*)d_in[5];
    const float* W3  = (const float*)d_in[6];
    const float* b3  = (const float*)d_in[7];
    float* out = (float*)d_out;

    crpb_mfma10<<<NBLOCKS, THREADS, 0, stream>>>(gq, gkv, W1, b1, W2, b2, W3, b3, out);
}

// Round 12
// 125.414 us; speedup vs baseline: 1.0634x; 1.0634x over previous
//
#include <hip/hip_runtime.h>
#include <math.h>

// ---------------- problem constants ----------------
#define NDIM 128
#define TILE 64
#define NBLOCKS 1024
#define THREADS 512               // 8 waves/block
#define POS_PER_BLOCK 1024
#define ITERS 16                  // 64-pos tiles per block
#define CH 512                    // ushorts per k'-chunk: 64 pos * 8

typedef __attribute__((ext_vector_type(8)))  short  short8;   // MFMA A/B frag
typedef __attribute__((ext_vector_type(16))) float  float16;  // 32x32 C/D frag

// gfx950 packed f32x2 -> bf16x2 (RNE), single VALU instruction
__device__ __forceinline__ unsigned cvt_pk(float lo, float hi) {
    unsigned r;
    asm("v_cvt_pk_bf16_f32 %0, %1, %2" : "=v"(r) : "v"(lo), "v"(hi));
    return r;
}

// k'-chunk map (layer-2): chunk c (0..15), elem jj (0..7) -> channel.
__device__ __forceinline__ int kmap(int c, int jj) {
    return 32 * (c >> 2) + 16 * ((c >> 1) & 1) + 4 * (c & 1) + ((jj >> 2) << 3) + (jj & 3);
}

// r8 structure (best: 67.7us) with persistent bias registers replaced by
// K-slot folding (r9/r10-verified): b1 in layer-1 spare K-slots vs 1.0 B-slots;
// b2 as one extra K-step MFMA starting the L2 chain. -32 persistent VGPRs
// -> target 4 waves/SIMD at r8's VALU count.
__global__ __launch_bounds__(512, 4)
void crpb_mfma11(const float* __restrict__ gq,   // (512,3)
                 const float* __restrict__ gkv,  // (4,512,3)
                 const float* __restrict__ W1,   // (3,128)
                 const float* __restrict__ b1,   // (128,)
                 const float* __restrict__ W2,   // (128,128)
                 const float* __restrict__ b2,   // (128,)
                 const float* __restrict__ W3,   // (128,4)
                 const float* __restrict__ b3,   // (4,)
                 float* __restrict__ out)        // (16,512,512)
{
    __shared__ __align__(16) unsigned short ash[2][16 * CH];   // 2 x 16 KB, double-buffered
    __shared__ __align__(16) float red[2][4 * 4 * 64];         // 2 x 4 KB partials [ct][o][pos]

    const int tid  = threadIdx.x;
    const int lane = tid & 63;
    const int w    = __builtin_amdgcn_readfirstlane(tid >> 6);  // 0..7
    const int l31  = lane & 31;
    const int lh   = lane >> 5;
    const bool l0  = (lh == 0);

    const int ct = w & 3;             // out-ch tile (32 chs)
    const int ph = w >> 2;            // pos-half
    const int pofs = ph * 32 + l31;

    float16 z16;
    #pragma unroll
    for (int r = 0; r < 16; ++r) z16[r] = 0.0f;

    // ---- layer-1 A-frag (4 VGPRs): W1 hi/lo + b1 folded in K-slots ----
    short8 w1f;
    {
        const int ch = ct * 32 + l31;
        const float w0 = W1[ch], w1v = W1[128 + ch], w2v = W1[256 + ch], b1v = b1[ch];
        const float w0h = __uint_as_float(cvt_pk(w0, w0) << 16);
        const float w1h = __uint_as_float(cvt_pk(w1v, w1v) << 16);
        const float w2h = __uint_as_float(cvt_pk(w2v, w2v) << 16);
        const float b1h = __uint_as_float(cvt_pk(b1v, b1v) << 16);
        const float w0l = w0 - w0h, w1l = w1v - w1h, w2l = w2v - w2h, b1l = b1v - b1h;
        unsigned d[4];
        d[0] = l0 ? cvt_pk(w0h, w0l) : cvt_pk(w2h, b1h);
        d[1] = l0 ? cvt_pk(w0h, w1h) : cvt_pk(b1l, 0.0f);
        d[2] = l0 ? cvt_pk(w1l, w1h) : 0u;
        d[3] = l0 ? cvt_pk(w2h, w2l) : 0u;
        __builtin_memcpy(&w1f, d, 16);
    }

    // ---- W2^T A-frags (k'-permuted), 32 VGPRs ----
    short8 a2f[8];
    #pragma unroll
    for (int ks = 0; ks < 8; ++ks) {
        const int c = 2 * ks + lh;
        unsigned t0[4];
        #pragma unroll
        for (int t = 0; t < 4; ++t) {
            const int d0 = kmap(c, 2 * t), d1 = d0 + 1;
            t0[t] = cvt_pk(W2[d0 * 128 + ct * 32 + l31], W2[d1 * 128 + ct * 32 + l31]);
        }
        __builtin_memcpy(&a2f[ks], t0, 16);
    }

    // ---- b2 K-step frag (4 VGPRs) + constant-1 B (4 VGPRs) ----
    short8 a2b2;
    {
        const float b2v = b2[ct * 32 + l31];
        const float b2h = __uint_as_float(cvt_pk(b2v, b2v) << 16);
        const float b2l = b2v - b2h;
        unsigned d[4];
        d[0] = l0 ? cvt_pk(b2h, b2l) : 0u;
        d[1] = 0; d[2] = 0; d[3] = 0;
        __builtin_memcpy(&a2b2, d, 16);
    }
    short8 bconst;
    {
        unsigned d[4];
        d[0] = l0 ? 0x3F803F80u : 0u;   // bf16(1.0) x2 in K-slots 0,1
        d[1] = 0; d[2] = 0; d[3] = 0;
        __builtin_memcpy(&bconst, d, 16);
    }

    // ---- W3 A-frags for in-register layer 3 (8 VGPRs), r9-verified mapping ----
    short8 w3a[2];
    #pragma unroll
    for (int m = 0; m < 2; ++m) {
        unsigned tt[4];
        #pragma unroll
        for (int t = 0; t < 4; ++t) {
            const int chl = ((2 * t) & 3) + 8 * ((2 * t) >> 2) + 4 * lh + 16 * m;
            const int ch0 = ct * 32 + chl, ch1 = ch0 + 1;
            const float lo = (l31 < 4) ? W3[ch0 * 4 + l31] : 0.0f;
            const float hi = (l31 < 4) ? W3[ch1 * 4 + l31] : 0.0f;
            tt[t] = cvt_pk(lo, hi);
        }
        __builtin_memcpy(&w3a[m], tt, 16);
    }
    const float b3r = b3[(tid >> 6) & 3];   // phase R: o = tid>>6 (tid<256)

    // block-constant: 1024 consecutive positions (same b)
    const int posblock = blockIdx.x * POS_PER_BLOCK;
    const int bb = posblock >> 18;
    const float* kvrow = gkv + (size_t)(bb << 9) * 3;

    // prefetch tile 0's q and kv
    int ii = (posblock >> 9) & 511;
    float q0 = gq[ii * 3 + 0], q1 = gq[ii * 3 + 1], q2 = gq[ii * 3 + 2];
    const float* kp = kvrow + (size_t)((posblock & 511) + pofs) * 3;
    float kv0 = kp[0], kv1 = kp[1], kv2 = kp[2];

    // ======== phase A: features -> hi/lo B-frag -> layer-1 MFMA -> ash[buf] ========
    auto phaseA = [&](int x, int buf) {
        const float c0 = q0 - kv0, c1 = q1 - kv1, c2 = q2 - kv2;
        const int pn = posblock + (((x + 1) & 15) << 6);
        const int iN = (pn >> 9) & 511, jN = pn & 511;
        q0 = gq[iN * 3 + 0]; q1 = gq[iN * 3 + 1]; q2 = gq[iN * 3 + 2];
        const float* kn = kvrow + (size_t)(jN + pofs) * 3;
        kv0 = kn[0]; kv1 = kn[1]; kv2 = kn[2];

        const float f0 = copysignf(__logf(1.0f + fabsf(c0)), c0);
        const float f1 = copysignf(__logf(1.0f + fabsf(c1)), c1);
        const float f2 = copysignf(__logf(1.0f + fabsf(c2)), c2);
        const unsigned u0 = cvt_pk(f0, f0), u2 = cvt_pk(f2, f2);
        const float f0h = __uint_as_float(u0 << 16);
        const float f1h = __uint_as_float(cvt_pk(f1, f1) << 16);
        const float f2h = __uint_as_float(u2 << 16);
        const float f0l = f0 - f0h, f1l = f1 - f1h, f2l = f2 - f2h;

        unsigned d[4];
        d[0] = l0 ? u0 : cvt_pk(f2l, 1.0f);        // lh1 1.0 slots pick up b1
        d[1] = l0 ? cvt_pk(f0l, f1) : 0x00003F80u; // (1.0, 0) for lh1
        d[2] = l0 ? cvt_pk(f1, f1l) : 0u;
        d[3] = l0 ? u2 : 0u;
        short8 bf; __builtin_memcpy(&bf, d, 16);

        // layer 1: h1 = W1e . fe (b1 via K-slots), 32 ch x 32 pos per wave
        float16 c1r = __builtin_amdgcn_mfma_f32_32x32x16_bf16(w1f, bf, z16, 0, 0, 0);

        // relu -> bf16 -> ash chunks (chunk = 4ct + 2m + lh), single b128 per m
        unsigned pk0[4], pk1[4];
        #pragma unroll
        for (int t = 0; t < 4; ++t) {
            pk0[t] = cvt_pk(fmaxf(c1r[2 * t], 0.f),     fmaxf(c1r[2 * t + 1], 0.f));
            pk1[t] = cvt_pk(fmaxf(c1r[8 + 2 * t], 0.f), fmaxf(c1r[8 + 2 * t + 1], 0.f));
        }
        short8 v0, v1;
        __builtin_memcpy(&v0, pk0, 16);
        __builtin_memcpy(&v1, pk1, 16);
        *(short8*)&ash[buf][(4 * ct + lh) * CH + pofs * 8]     = v0;   // m=0
        *(short8*)&ash[buf][(4 * ct + 2 + lh) * CH + pofs * 8] = v1;   // m=1
    };

    phaseA(0, 0);
    __syncthreads();

    for (int it = 0; it < ITERS; ++it) {
        const int buf = it & 1;
        const int posbase = posblock + it * TILE;
        const int i  = (posbase >> 9) & 511;
        const int jb = posbase & 511;

        // ======== phase B: b2 K-step starts the chain; then 8 L2 MFMAs ========
        const unsigned short* br = &ash[buf][lh * CH + (ph * 32 + l31) * 8];
        float16 acc = __builtin_amdgcn_mfma_f32_32x32x16_bf16(a2b2, bconst, z16, 0, 0, 0);
        #pragma unroll
        for (int ks = 0; ks < 8; ++ks) {
            short8 bfrag = *(const short8*)(br + ks * 2 * CH);
            acc = __builtin_amdgcn_mfma_f32_32x32x16_bf16(a2f[ks], bfrag, acc, 0, 0, 0);
        }

        // ======== phase C': in-register relu + layer-3 MFMA + partial write ========
        {
            unsigned pk0[4], pk1[4];
            #pragma unroll
            for (int t = 0; t < 4; ++t) {
                pk0[t] = cvt_pk(fmaxf(acc[2 * t], 0.f),     fmaxf(acc[2 * t + 1], 0.f));
                pk1[t] = cvt_pk(fmaxf(acc[8 + 2 * t], 0.f), fmaxf(acc[8 + 2 * t + 1], 0.f));
            }
            short8 bm0, bm1;
            __builtin_memcpy(&bm0, pk0, 16);
            __builtin_memcpy(&bm1, pk1, 16);
            float16 p;
            p = __builtin_amdgcn_mfma_f32_32x32x16_bf16(w3a[0], bm0, z16, 0, 0, 0);
            p = __builtin_amdgcn_mfma_f32_32x32x16_bf16(w3a[1], bm1, p, 0, 0, 0);
            if (l0) {
                #pragma unroll
                for (int o = 0; o < 4; ++o)
                    red[buf][(ct * 4 + o) * 64 + ph * 32 + l31] = p[o];
            }
        }

        // ======== phase A for next tile (other ash buffer) ========
        if (it != ITERS - 1) phaseA(it + 1, 1 - buf);

        __syncthreads();   // single barrier/tile: fences ash[1-buf] and red[buf]

        // ======== phase R: cross-wave reduce + coalesced store ========
        if (tid < 256) {
            const int o = tid >> 6, pos = tid & 63;
            const float* rb = &red[buf][o * 64 + pos];
            const float v = b3r + rb[0] + rb[256] + rb[512] + rb[768];
            out[((size_t)((bb << 2) + o) << 18) + ((size_t)i << 9) + jb + pos] = v;
        }
    }
}

extern "C" void kernel_launch(void* const* d_in, const int* in_sizes, int n_in,
                              void* d_out, int out_size, void* d_ws, size_t ws_size,
                              hipStream_t stream) {
    const float* gq  = (const float*)d_in[0];
    const float* gkv = (const float*)d_in[1];
    const float* W1  = (const float*)d_in[2];
    const float* b1  = (const float*)d_in[3];
    const float* W2  = (const float*)d_in[4];
    const float* b2  = (const float*)d_in[5];
    const float* W3  = (const float*)d_in[6];
    const float* b3  = (const float*)d_in[7];
    float* out = (float*)d_out;

    crpb_mfma11<<<NBLOCKS, THREADS, 0, stream>>>(gq, gkv, W1, b1, W2, b2, W3, b3, out);
}